// Round 10
// baseline (106.549 us; speedup 1.0000x reference)
//
#include <hip/hip_runtime.h>
#include <hip/hip_bf16.h>

constexpr int N_NODES = 100000;
constexpr int DIM     = 128;
constexpr int N_EDGES = 640000;

constexpr int CHUNK     = 1024;
constexpr int N_CHUNKS  = (N_NODES + CHUNK - 1) / CHUNK;   // 98
constexpr int BINCAP    = 8192;
constexpr int EPB       = 1024;
constexpr int SRC_BITS  = 17;
constexpr int SRC_MASK  = (1 << SRC_BITS) - 1;

constexpr int XCONV_XBLOCKS = N_NODES * DIM / (256 * 8);   // 6250
constexpr int XCONV_WBLOCKS = DIM * DIM / (256 * 8);       // 8

constexpr int GNB  = 32;                                   // nodes per gmm block
constexpr int HPAD = DIM + 8;                              // 136 bf16 rows

typedef __attribute__((ext_vector_type(4))) float        f32x4;
typedef __attribute__((ext_vector_type(8))) short        bf16x8;
typedef __attribute__((ext_vector_type(4))) unsigned int u32x4;

static __device__ inline unsigned short f2bf(float f) {
    __hip_bfloat16 h = __float2bfloat16(f);   // RNE
    return *reinterpret_cast<unsigned short*>(&h);
}
static __device__ inline float bf_lo(unsigned u) { return __uint_as_float(u << 16); }
static __device__ inline float bf_hi(unsigned u) { return __uint_as_float(u & 0xffff0000u); }

// ---------------------------------------------------------------------------
// 1) Fused: x->bf16 (-> ws), W->bf16, zero the 98 bin cursors.
// ---------------------------------------------------------------------------
__global__ __launch_bounds__(256) void gcn_conv(const float* __restrict__ x,
                                                const float* __restrict__ W,
                                                unsigned int* __restrict__ xb,
                                                unsigned int* __restrict__ wb,
                                                int* __restrict__ bincur)
{
    const int b   = blockIdx.x;
    const int gid = b * 256 + threadIdx.x;

    if (b == 0 && threadIdx.x < 128) bincur[threadIdx.x] = 0;

    const float*  src;
    unsigned int* dst;
    int i;
    if (b < XCONV_XBLOCKS) {
        src = x;  dst = xb;  i = gid;
    } else {
        src = W;  dst = wb;  i = gid - XCONV_XBLOCKS * 256;
    }
    const f32x4* s4 = reinterpret_cast<const f32x4*>(src);
    f32x4 a = s4[2 * i];
    f32x4 c = s4[2 * i + 1];
    u32x4 o;
    o.x = (unsigned)f2bf(a.x) | ((unsigned)f2bf(a.y) << 16);
    o.y = (unsigned)f2bf(a.z) | ((unsigned)f2bf(a.w) << 16);
    o.z = (unsigned)f2bf(c.x) | ((unsigned)f2bf(c.y) << 16);
    o.w = (unsigned)f2bf(c.z) | ((unsigned)f2bf(c.w) << 16);
    reinterpret_cast<u32x4*>(dst)[i] = o;
}

// ---------------------------------------------------------------------------
// 2) Bin pass: scatter edges into per-chunk regions (packed src|dstlocal).
// ---------------------------------------------------------------------------
__global__ __launch_bounds__(256) void gcn_bin(const int* __restrict__ src,
                                               const int* __restrict__ dst,
                                               int* __restrict__ bincur,
                                               unsigned int* __restrict__ bindata)
{
    __shared__ int bh[N_CHUNKS];
    __shared__ int btb[N_CHUNKS];

    const int t  = threadIdx.x;
    const int e0 = blockIdx.x * EPB + t * 4;

    if (t < N_CHUNKS) bh[t] = 0;
    __syncthreads();

    const int4 s4 = *reinterpret_cast<const int4*>(src + e0);
    const int4 d4 = *reinterpret_cast<const int4*>(dst + e0);

    int bin[4], pos[4];
    unsigned pv[4];
    const int ds[4] = {d4.x, d4.y, d4.z, d4.w};
    const int ss[4] = {s4.x, s4.y, s4.z, s4.w};
    #pragma unroll
    for (int q = 0; q < 4; ++q) {
        bin[q] = ds[q] >> 10;
        pv[q]  = (unsigned)ss[q] | ((unsigned)(ds[q] & (CHUNK - 1)) << SRC_BITS);
        pos[q] = atomicAdd(&bh[bin[q]], 1);
    }
    __syncthreads();

    if (t < N_CHUNKS) btb[t] = atomicAdd(&bincur[t], bh[t]);
    __syncthreads();

    #pragma unroll
    for (int q = 0; q < 4; ++q)
        bindata[(size_t)bin[q] * BINCAP + btb[bin[q]] + pos[q]] = pv[q];
}

// ---------------------------------------------------------------------------
// 3) Build pass: per-chunk LDS counting sort -> dense csr + off metadata.
// ---------------------------------------------------------------------------
__global__ __launch_bounds__(256) void gcn_build(const int* __restrict__ bincur,
                                                 unsigned int* __restrict__ bindata,
                                                 int* __restrict__ off)
{
    __shared__ unsigned stage[BINCAP];
    __shared__ int hist[CHUNK];
    __shared__ int s[256];

    const int c  = blockIdx.x;
    const int t  = threadIdx.x;
    const int nb = min(bincur[c], BINCAP);
    unsigned int* region = bindata + (size_t)c * BINCAP;

    for (int e = t; e < nb; e += 256) stage[e] = region[e];
    #pragma unroll
    for (int q = 0; q < 4; ++q) hist[t + 256 * q] = 0;
    __syncthreads();

    for (int e = t; e < nb; e += 256)
        atomicAdd(&hist[stage[e] >> SRC_BITS], 1);
    __syncthreads();

    int h0 = hist[4 * t + 0], h1 = hist[4 * t + 1];
    int h2 = hist[4 * t + 2], h3 = hist[4 * t + 3];
    s[t] = h0 + h1 + h2 + h3;
    __syncthreads();
    for (int d = 1; d < 256; d <<= 1) {
        int add = (t >= d) ? s[t - d] : 0;
        __syncthreads();
        s[t] += add;
        __syncthreads();
    }
    int excl = (t > 0) ? s[t - 1] : 0;

    const int st0 = excl;
    const int st1 = excl + h0;
    const int st2 = excl + h0 + h1;
    const int st3 = excl + h0 + h1 + h2;
    hist[4 * t + 0] = st0;  hist[4 * t + 1] = st1;
    hist[4 * t + 2] = st2;  hist[4 * t + 3] = st3;

    const int nbase = c * CHUNK;
    if (nbase + 4 * t + 0 < N_NODES) off[nbase + 4 * t + 0] = st0 | (h0 << 13);
    if (nbase + 4 * t + 1 < N_NODES) off[nbase + 4 * t + 1] = st1 | (h1 << 13);
    if (nbase + 4 * t + 2 < N_NODES) off[nbase + 4 * t + 2] = st2 | (h2 << 13);
    if (nbase + 4 * t + 3 < N_NODES) off[nbase + 4 * t + 3] = st3 | (h3 << 13);
    __syncthreads();

    for (int e = t; e < nb; e += 256) {
        unsigned v  = stage[e];
        int slot    = atomicAdd(&hist[v >> SRC_BITS], 1);
        region[slot] = v & SRC_MASK;
    }
}

// ---------------------------------------------------------------------------
// 4) FUSED gather + MFMA, 32 nodes/block, DUAL interleaved gather chains.
//    Phase A: thread (nloc, lane16) gathers slices of nodes nloc AND nloc+16
//    with lockstep-interleaved loads (8 independent 16B gathers in flight).
//    Phase B: wave w -> row-tile (w&1), c-cols [4*(w>>1), +4), 16 MFMAs.
// ---------------------------------------------------------------------------
static __device__ inline void acc8(float* acc, u32x4 v) {
    #pragma unroll
    for (int q = 0; q < 4; ++q) {
        unsigned u = v[q];
        acc[2 * q]     += bf_lo(u);
        acc[2 * q + 1] += bf_hi(u);
    }
}

__global__ __launch_bounds__(256) void gcn_gmm(
    const unsigned short* __restrict__ xb,
    const int* __restrict__ off,
    const unsigned int* __restrict__ csr,
    const unsigned short* __restrict__ wb,
    const float* __restrict__ bias,
    float* __restrict__ out)
{
    __shared__ unsigned short hl[GNB][HPAD];   // 8.7 KB

    const int tid    = threadIdx.x;
    const int n0     = blockIdx.x * GNB;       // grid exact: 3125 blocks
    const int nloc   = tid >> 4;               // 0..15
    const int lane16 = tid & 15;
    const int col8   = lane16 * 8;
    const int nA     = n0 + nloc;
    const int nB     = n0 + 16 + nloc;

    // ---- Phase A: dual-node gather ----
    {
        const int metaA  = off[nA];
        const int metaB  = off[nB];
        const int cntA   = metaA >> 13;
        const int cntB   = metaB >> 13;
        int iA = (nA >> 10) * BINCAP + (metaA & (BINCAP - 1));
        int iB = (nB >> 10) * BINCAP + (metaB & (BINCAP - 1));
        const int endA = iA + cntA;
        const int endB = iB + cntB;

        float accA[8], accB[8];
        #pragma unroll
        for (int q = 0; q < 8; ++q) { accA[q] = 0.0f; accB[q] = 0.0f; }

        // lockstep: 8 independent gathers in flight
        while (iA + 4 <= endA && iB + 4 <= endB) {
            const int4 ia4 = *reinterpret_cast<const int4*>(csr + iA);
            const int4 ib4 = *reinterpret_cast<const int4*>(csr + iB);
            u32x4 a0 = *reinterpret_cast<const u32x4*>(xb + (size_t)ia4.x * DIM + col8);
            u32x4 a1 = *reinterpret_cast<const u32x4*>(xb + (size_t)ia4.y * DIM + col8);
            u32x4 a2 = *reinterpret_cast<const u32x4*>(xb + (size_t)ia4.z * DIM + col8);
            u32x4 a3 = *reinterpret_cast<const u32x4*>(xb + (size_t)ia4.w * DIM + col8);
            u32x4 b0 = *reinterpret_cast<const u32x4*>(xb + (size_t)ib4.x * DIM + col8);
            u32x4 b1 = *reinterpret_cast<const u32x4*>(xb + (size_t)ib4.y * DIM + col8);
            u32x4 b2 = *reinterpret_cast<const u32x4*>(xb + (size_t)ib4.z * DIM + col8);
            u32x4 b3 = *reinterpret_cast<const u32x4*>(xb + (size_t)ib4.w * DIM + col8);
            acc8(accA, a0); acc8(accA, a1); acc8(accA, a2); acc8(accA, a3);
            acc8(accB, b0); acc8(accB, b1); acc8(accB, b2); acc8(accB, b3);
            iA += 4; iB += 4;
        }
        // finish A
        for (; iA + 4 <= endA; iA += 4) {
            const int4 i4 = *reinterpret_cast<const int4*>(csr + iA);
            u32x4 v0 = *reinterpret_cast<const u32x4*>(xb + (size_t)i4.x * DIM + col8);
            u32x4 v1 = *reinterpret_cast<const u32x4*>(xb + (size_t)i4.y * DIM + col8);
            u32x4 v2 = *reinterpret_cast<const u32x4*>(xb + (size_t)i4.z * DIM + col8);
            u32x4 v3 = *reinterpret_cast<const u32x4*>(xb + (size_t)i4.w * DIM + col8);
            acc8(accA, v0); acc8(accA, v1); acc8(accA, v2); acc8(accA, v3);
        }
        for (; iA < endA; ++iA) {
            u32x4 v = *reinterpret_cast<const u32x4*>(xb + (size_t)csr[iA] * DIM + col8);
            acc8(accA, v);
        }
        // finish B
        for (; iB + 4 <= endB; iB += 4) {
            const int4 i4 = *reinterpret_cast<const int4*>(csr + iB);
            u32x4 v0 = *reinterpret_cast<const u32x4*>(xb + (size_t)i4.x * DIM + col8);
            u32x4 v1 = *reinterpret_cast<const u32x4*>(xb + (size_t)i4.y * DIM + col8);
            u32x4 v2 = *reinterpret_cast<const u32x4*>(xb + (size_t)i4.z * DIM + col8);
            u32x4 v3 = *reinterpret_cast<const u32x4*>(xb + (size_t)i4.w * DIM + col8);
            acc8(accB, v0); acc8(accB, v1); acc8(accB, v2); acc8(accB, v3);
        }
        for (; iB < endB; ++iB) {
            u32x4 v = *reinterpret_cast<const u32x4*>(xb + (size_t)csr[iB] * DIM + col8);
            acc8(accB, v);
        }

        const float invA = 1.0f / fmaxf((float)cntA, 1.0f);
        const float invB = 1.0f / fmaxf((float)cntB, 1.0f);
        const u32x4 xrA = *reinterpret_cast<const u32x4*>(xb + (size_t)nA * DIM + col8);
        const u32x4 xrB = *reinterpret_cast<const u32x4*>(xb + (size_t)nB * DIM + col8);
        u32x4 oA, oB;
        #pragma unroll
        for (int q = 0; q < 4; ++q) {
            float a0 = accA[2 * q]     * invA + bf_lo(xrA[q]);
            float a1 = accA[2 * q + 1] * invA + bf_hi(xrA[q]);
            float b0 = accB[2 * q]     * invB + bf_lo(xrB[q]);
            float b1 = accB[2 * q + 1] * invB + bf_hi(xrB[q]);
            oA[q] = (unsigned)f2bf(a0) | ((unsigned)f2bf(a1) << 16);
            oB[q] = (unsigned)f2bf(b0) | ((unsigned)f2bf(b1) << 16);
        }
        *reinterpret_cast<u32x4*>(&hl[nloc][col8])      = oA;
        *reinterpret_cast<u32x4*>(&hl[nloc + 16][col8]) = oB;
    }
    __syncthreads();

    // ---- Phase B: wave w -> row-tile (w&1), c-cols [4*(w>>1), +4) ----
    const int w    = tid >> 6;
    const int lane = tid & 63;
    const int r    = lane & 15;
    const int g    = lane >> 4;
    const int rowt  = w & 1;
    const int cbase = 4 * (w >> 1);

    bf16x8 af[4];
    #pragma unroll
    for (int t = 0; t < 4; ++t)
        af[t] = *reinterpret_cast<const bf16x8*>(&hl[16 * rowt + r][32 * t + 8 * g]);

    #pragma unroll
    for (int cc = 0; cc < 4; ++cc) {
        const int c = cbase + cc;
        f32x4 acc = {0.f, 0.f, 0.f, 0.f};
        #pragma unroll
        for (int t = 0; t < 4; ++t) {
            bf16x8 wf = *reinterpret_cast<const bf16x8*>(
                wb + (16 * c + r) * DIM + 32 * t + 8 * g);
            acc = __builtin_amdgcn_mfma_f32_16x16x32_bf16(af[t], wf, acc, 0, 0, 0);
        }
        const float bj = bias[16 * c + r];
        #pragma unroll
        for (int q = 0; q < 4; ++q)
            out[(size_t)(n0 + 16 * rowt + 4 * g + q) * DIM + 16 * c + r] =
                fmaxf(acc[q] + bj, 0.0f);
    }
}

// ---------------------------------------------------------------------------
extern "C" void kernel_launch(void* const* d_in, const int* in_sizes, int n_in,
                              void* d_out, int out_size, void* d_ws, size_t ws_size,
                              hipStream_t stream)
{
    const float* x    = (const float*)d_in[0];
    const int*   eidx = (const int*)d_in[1];
    const float* W    = (const float*)d_in[2];
    const float* bias = (const float*)d_in[3];
    float*       out  = (float*)d_out;

    const int* src = eidx;
    const int* dst = eidx + N_EDGES;

    int* bincur = (int*)d_ws;                               // [128]
    int* off    = bincur + 128;                             // [N]
    unsigned int* bindata = (unsigned int*)(off + 100352);  // [98*8192] -> becomes csr
    unsigned short* wb = (unsigned short*)(bindata + (size_t)N_CHUNKS * BINCAP);
    unsigned short* xb = wb + (size_t)DIM * DIM;            // [N*128] bf16

    gcn_conv <<<XCONV_XBLOCKS + XCONV_WBLOCKS, 256, 0, stream>>>(
        x, W, (unsigned int*)xb, (unsigned int*)wb, bincur);
    gcn_bin  <<<N_EDGES / EPB, 256, 0, stream>>>(src, dst, bincur, bindata);
    gcn_build<<<N_CHUNKS, 256, 0, stream>>>(bincur, bindata, off);
    gcn_gmm  <<<N_NODES / GNB, 256, 0, stream>>>(
        xb, off, bindata, wb, bias, out);
}

// Round 11
// 90.316 us; speedup vs baseline: 1.1797x; 1.1797x over previous
//
#include <hip/hip_runtime.h>
#include <hip/hip_bf16.h>

constexpr int N_NODES = 100000;
constexpr int DIM     = 128;
constexpr int N_EDGES = 640000;

constexpr int CHUNK     = 1024;
constexpr int N_CHUNKS  = (N_NODES + CHUNK - 1) / CHUNK;   // 98
constexpr int BINCAP    = 8192;
constexpr int EPB       = 1024;
constexpr int SRC_BITS  = 17;
constexpr int SRC_MASK  = (1 << SRC_BITS) - 1;

constexpr int YNB = 32;                                    // nodes per gemm block

typedef __attribute__((ext_vector_type(4))) float        f32x4;
typedef __attribute__((ext_vector_type(8))) short        bf16x8;
typedef __attribute__((ext_vector_type(4))) unsigned int u32x4;

static __device__ inline unsigned short f2bf(float f) {
    __hip_bfloat16 h = __float2bfloat16(f);   // RNE
    return *reinterpret_cast<unsigned short*>(&h);
}
static __device__ inline float bf_lo(unsigned u) { return __uint_as_float(u << 16); }
static __device__ inline float bf_hi(unsigned u) { return __uint_as_float(u & 0xffff0000u); }

static __device__ inline bf16x8 pack8(f32x4 a, f32x4 b) {
    bf16x8 v;
    v[0] = (short)f2bf(a.x); v[1] = (short)f2bf(a.y);
    v[2] = (short)f2bf(a.z); v[3] = (short)f2bf(a.w);
    v[4] = (short)f2bf(b.x); v[5] = (short)f2bf(b.y);
    v[6] = (short)f2bf(b.z); v[7] = (short)f2bf(b.w);
    return v;
}

// ---------------------------------------------------------------------------
// 1) Dense GEMM: y = bf16( x @ W^T )  (no bias/relu here — applied in agg).
//    32 nodes/block. W staged f32->bf16 into LDS once per block (L2-hot).
//    A-frags read f32 x directly, converted in-register. Block 0 also zeroes
//    the 98 bin cursors (runs before gcn_bin in stream order).
// ---------------------------------------------------------------------------
__global__ __launch_bounds__(256) void gcn_gemm_y(
    const float* __restrict__ x,
    const float* __restrict__ W,
    unsigned short* __restrict__ y,
    int* __restrict__ bincur)
{
    __shared__ unsigned short wl[DIM][DIM + 8];   // 34.8 KB

    const int tid = threadIdx.x;
    const int n0  = blockIdx.x * YNB;             // grid exact: 3125 blocks

    if (blockIdx.x == 0 && tid < 128) bincur[tid] = 0;

    // Stage W: 16384 f32 -> bf16 LDS, 64 elems/thread, coalesced 32B loads
    #pragma unroll
    for (int rep = 0; rep < 8; ++rep) {
        const int e   = rep * 2048 + tid * 8;
        const int row = e >> 7;
        const int col = e & 127;
        f32x4 a = *reinterpret_cast<const f32x4*>(W + e);
        f32x4 b = *reinterpret_cast<const f32x4*>(W + e + 4);
        *reinterpret_cast<bf16x8*>(&wl[row][col]) = pack8(a, b);
    }
    __syncthreads();

    const int w    = tid >> 6;
    const int lane = tid & 63;
    const int r    = lane & 15;
    const int g    = lane >> 4;
    const int rowt  = w & 1;                      // row-tile 0/1 (16 rows each)
    const int cbase = 4 * (w >> 1);               // c-groups 0..3 / 4..7

    // A-frags from global f32 x, converted in-register
    bf16x8 af[4];
    #pragma unroll
    for (int t = 0; t < 4; ++t) {
        const float* xp = x + (size_t)(n0 + 16 * rowt + r) * DIM + 32 * t + 8 * g;
        f32x4 a = *reinterpret_cast<const f32x4*>(xp);
        f32x4 b = *reinterpret_cast<const f32x4*>(xp + 4);
        af[t] = pack8(a, b);
    }

    #pragma unroll
    for (int cc = 0; cc < 4; ++cc) {
        const int c = cbase + cc;
        f32x4 acc = {0.f, 0.f, 0.f, 0.f};
        #pragma unroll
        for (int t = 0; t < 4; ++t) {
            bf16x8 wf = *reinterpret_cast<const bf16x8*>(&wl[16 * c + r][32 * t + 8 * g]);
            acc = __builtin_amdgcn_mfma_f32_16x16x32_bf16(af[t], wf, acc, 0, 0, 0);
        }
        #pragma unroll
        for (int q = 0; q < 4; ++q)
            y[(size_t)(n0 + 16 * rowt + 4 * g + q) * DIM + 16 * c + r] =
                f2bf(acc[q]);
    }
}

// ---------------------------------------------------------------------------
// 2) Bin pass: scatter edges into per-chunk regions (packed src|dstlocal).
// ---------------------------------------------------------------------------
__global__ __launch_bounds__(256) void gcn_bin(const int* __restrict__ src,
                                               const int* __restrict__ dst,
                                               int* __restrict__ bincur,
                                               unsigned int* __restrict__ bindata)
{
    __shared__ int bh[N_CHUNKS];
    __shared__ int btb[N_CHUNKS];

    const int t  = threadIdx.x;
    const int e0 = blockIdx.x * EPB + t * 4;

    if (t < N_CHUNKS) bh[t] = 0;
    __syncthreads();

    const int4 s4 = *reinterpret_cast<const int4*>(src + e0);
    const int4 d4 = *reinterpret_cast<const int4*>(dst + e0);

    int bin[4], pos[4];
    unsigned pv[4];
    const int ds[4] = {d4.x, d4.y, d4.z, d4.w};
    const int ss[4] = {s4.x, s4.y, s4.z, s4.w};
    #pragma unroll
    for (int q = 0; q < 4; ++q) {
        bin[q] = ds[q] >> 10;
        pv[q]  = (unsigned)ss[q] | ((unsigned)(ds[q] & (CHUNK - 1)) << SRC_BITS);
        pos[q] = atomicAdd(&bh[bin[q]], 1);
    }
    __syncthreads();

    if (t < N_CHUNKS) btb[t] = atomicAdd(&bincur[t], bh[t]);
    __syncthreads();

    #pragma unroll
    for (int q = 0; q < 4; ++q)
        bindata[(size_t)bin[q] * BINCAP + btb[bin[q]] + pos[q]] = pv[q];
}

// ---------------------------------------------------------------------------
// 3) Build pass: per-chunk LDS counting sort -> dense csr + off metadata.
// ---------------------------------------------------------------------------
__global__ __launch_bounds__(256) void gcn_build(const int* __restrict__ bincur,
                                                 unsigned int* __restrict__ bindata,
                                                 int* __restrict__ off)
{
    __shared__ unsigned stage[BINCAP];
    __shared__ int hist[CHUNK];
    __shared__ int s[256];

    const int c  = blockIdx.x;
    const int t  = threadIdx.x;
    const int nb = min(bincur[c], BINCAP);
    unsigned int* region = bindata + (size_t)c * BINCAP;

    for (int e = t; e < nb; e += 256) stage[e] = region[e];
    #pragma unroll
    for (int q = 0; q < 4; ++q) hist[t + 256 * q] = 0;
    __syncthreads();

    for (int e = t; e < nb; e += 256)
        atomicAdd(&hist[stage[e] >> SRC_BITS], 1);
    __syncthreads();

    int h0 = hist[4 * t + 0], h1 = hist[4 * t + 1];
    int h2 = hist[4 * t + 2], h3 = hist[4 * t + 3];
    s[t] = h0 + h1 + h2 + h3;
    __syncthreads();
    for (int d = 1; d < 256; d <<= 1) {
        int add = (t >= d) ? s[t - d] : 0;
        __syncthreads();
        s[t] += add;
        __syncthreads();
    }
    int excl = (t > 0) ? s[t - 1] : 0;

    const int st0 = excl;
    const int st1 = excl + h0;
    const int st2 = excl + h0 + h1;
    const int st3 = excl + h0 + h1 + h2;
    hist[4 * t + 0] = st0;  hist[4 * t + 1] = st1;
    hist[4 * t + 2] = st2;  hist[4 * t + 3] = st3;

    const int nbase = c * CHUNK;
    if (nbase + 4 * t + 0 < N_NODES) off[nbase + 4 * t + 0] = st0 | (h0 << 13);
    if (nbase + 4 * t + 1 < N_NODES) off[nbase + 4 * t + 1] = st1 | (h1 << 13);
    if (nbase + 4 * t + 2 < N_NODES) off[nbase + 4 * t + 2] = st2 | (h2 << 13);
    if (nbase + 4 * t + 3 < N_NODES) off[nbase + 4 * t + 3] = st3 | (h3 << 13);
    __syncthreads();

    for (int e = t; e < nb; e += 256) {
        unsigned v  = stage[e];
        int slot    = atomicAdd(&hist[v >> SRC_BITS], 1);
        region[slot] = v & SRC_MASK;
    }
}

// ---------------------------------------------------------------------------
// 4) Pure gather in y-space: out[n] = relu( sum(y[src])/max(deg,1) + y[n] + b ).
//    16 lanes/node, 16B/lane, 4-deep unroll. NO LDS, NO barrier — waves
//    fully independent (R9 geometry, minus the Phase-B tail).
// ---------------------------------------------------------------------------
static __device__ inline void acc8(float* acc, u32x4 v) {
    #pragma unroll
    for (int q = 0; q < 4; ++q) {
        unsigned u = v[q];
        acc[2 * q]     += bf_lo(u);
        acc[2 * q + 1] += bf_hi(u);
    }
}

__global__ __launch_bounds__(256) void gcn_agg(
    const unsigned short* __restrict__ y,
    const int* __restrict__ off,
    const unsigned int* __restrict__ csr,
    const float* __restrict__ bias,
    float* __restrict__ out)
{
    const int tid    = threadIdx.x;
    const int lane16 = tid & 15;
    const int n      = blockIdx.x * 16 + (tid >> 4);   // grid exact: 6250
    const int col8   = lane16 * 8;

    const int meta  = off[n];
    const int count = meta >> 13;
    int i           = (n >> 10) * BINCAP + (meta & (BINCAP - 1));
    const int end   = i + count;

    float acc[8];
    #pragma unroll
    for (int q = 0; q < 8; ++q) acc[q] = 0.0f;

    for (; i + 4 <= end; i += 4) {
        int s0 = csr[i], s1 = csr[i + 1], s2 = csr[i + 2], s3 = csr[i + 3];
        u32x4 v0 = *reinterpret_cast<const u32x4*>(y + (size_t)s0 * DIM + col8);
        u32x4 v1 = *reinterpret_cast<const u32x4*>(y + (size_t)s1 * DIM + col8);
        u32x4 v2 = *reinterpret_cast<const u32x4*>(y + (size_t)s2 * DIM + col8);
        u32x4 v3 = *reinterpret_cast<const u32x4*>(y + (size_t)s3 * DIM + col8);
        acc8(acc, v0); acc8(acc, v1); acc8(acc, v2); acc8(acc, v3);
    }
    for (; i < end; ++i) {
        u32x4 v = *reinterpret_cast<const u32x4*>(y + (size_t)csr[i] * DIM + col8);
        acc8(acc, v);
    }

    const float inv = 1.0f / fmaxf((float)count, 1.0f);
    const u32x4 yr = *reinterpret_cast<const u32x4*>(y + (size_t)n * DIM + col8);
    const f32x4 b0 = *reinterpret_cast<const f32x4*>(bias + col8);
    const f32x4 b1 = *reinterpret_cast<const f32x4*>(bias + col8 + 4);

    f32x4 o0, o1;
    o0.x = fmaxf(acc[0] * inv + bf_lo(yr[0]) + b0.x, 0.0f);
    o0.y = fmaxf(acc[1] * inv + bf_hi(yr[0]) + b0.y, 0.0f);
    o0.z = fmaxf(acc[2] * inv + bf_lo(yr[1]) + b0.z, 0.0f);
    o0.w = fmaxf(acc[3] * inv + bf_hi(yr[1]) + b0.w, 0.0f);
    o1.x = fmaxf(acc[4] * inv + bf_lo(yr[2]) + b1.x, 0.0f);
    o1.y = fmaxf(acc[5] * inv + bf_hi(yr[2]) + b1.y, 0.0f);
    o1.z = fmaxf(acc[6] * inv + bf_lo(yr[3]) + b1.z, 0.0f);
    o1.w = fmaxf(acc[7] * inv + bf_hi(yr[3]) + b1.w, 0.0f);

    *reinterpret_cast<f32x4*>(out + (size_t)n * DIM + col8)     = o0;
    *reinterpret_cast<f32x4*>(out + (size_t)n * DIM + col8 + 4) = o1;
}

// ---------------------------------------------------------------------------
extern "C" void kernel_launch(void* const* d_in, const int* in_sizes, int n_in,
                              void* d_out, int out_size, void* d_ws, size_t ws_size,
                              hipStream_t stream)
{
    const float* x    = (const float*)d_in[0];
    const int*   eidx = (const int*)d_in[1];
    const float* W    = (const float*)d_in[2];
    const float* bias = (const float*)d_in[3];
    float*       out  = (float*)d_out;

    const int* src = eidx;
    const int* dst = eidx + N_EDGES;

    int* bincur = (int*)d_ws;                               // [128]
    int* off    = bincur + 128;                             // [N]
    unsigned int* bindata = (unsigned int*)(off + 100352);  // [98*8192] -> becomes csr
    unsigned short* y = (unsigned short*)(bindata + (size_t)N_CHUNKS * BINCAP); // [N*128] bf16

    gcn_gemm_y<<<N_NODES / YNB, 256, 0, stream>>>(x, W, y, bincur);
    gcn_bin   <<<N_EDGES / EPB, 256, 0, stream>>>(src, dst, bincur, bindata);
    gcn_build <<<N_CHUNKS, 256, 0, stream>>>(bincur, bindata, off);
    gcn_agg   <<<N_NODES / 16, 256, 0, stream>>>(y, off, bindata, bias, out);
}